// Round 4
// baseline (1493.490 us; speedup 1.0000x reference)
//
#include <hip/hip_runtime.h>

#define NE     800000
#define NWT    25000          // 32-edge wave-tiles
#define GRID   2048
#define HP     200            // ushort pitch (400 B row stride, +pad for banks)

typedef __attribute__((ext_vector_type(8))) short short8;   // 8 x bf16
typedef __attribute__((ext_vector_type(4))) float f32x4;

// f32 -> bf16 bits, round-to-nearest-even
__device__ __forceinline__ ushort f2b(float f) {
    unsigned u = __float_as_uint(f);
    return (ushort)((u + 0x7FFFu + ((u >> 16) & 1u)) >> 16);
}

// Pack W1 (192x192) and W2 (192x64) f32 -> bf16 MFMA B-fragments in d_ws.
// Entry e = t*6+k (e<72: W1; e>=72: W2). Lane l supplies
// B[k*32 + (l>>4)*8 + j][t*16 + (l&15)], j=0..7  (16 B per lane).
__global__ void pack_w(const float* __restrict__ W1, const float* __restrict__ W2,
                       uint4* __restrict__ wsW)
{
    int i = blockIdx.x * 256 + threadIdx.x;     // 0..6143
    int lane = i & 63, e = i >> 6;
    const float* W; int N, t, k;
    if (e < 72) { W = W1; N = 192; t = e / 6; k = e - t * 6; }
    else        { int e2 = e - 72; W = W2; N = 64; t = e2 / 6; k = e2 - t * 6; }
    const float* p = W + (size_t)(k * 32 + (lane >> 4) * 8) * N + t * 16 + (lane & 15);
    ushort u[8];
    #pragma unroll
    for (int j = 0; j < 8; ++j) u[j] = f2b(p[(size_t)j * N]);
    uint4 d;
    d.x = u[0] | ((unsigned)u[1] << 16);
    d.y = u[2] | ((unsigned)u[3] << 16);
    d.z = u[4] | ((unsigned)u[5] << 16);
    d.w = u[6] | ((unsigned)u[7] << 16);
    wsW[i] = d;
}

// One wave = one 32-edge tile, all 192 cols. No __syncthreads in the loop.
// LDS: wave-private X/H buffer only (4 x 12.8 KB = 51.2 KB/block -> 3 blocks/CU).
__global__ __launch_bounds__(256, 3)
void edge_kernel(const float* __restrict__ nf, const float* __restrict__ ef,
                 const int* __restrict__ ei,
                 const float* __restrict__ b1g, const float* __restrict__ gammag,
                 const float* __restrict__ betag, const float* __restrict__ b2g,
                 const uint4* __restrict__ wsW, float* __restrict__ out)
{
    __shared__ ushort Xs[4][32 * HP];
    const int tid = threadIdx.x, w = tid >> 6, lane = tid & 63;
    const int lrow = lane & 15, lg = lane >> 4, le = lane & 31;
    ushort* X = Xs[w];

    // per-lane LN/bias constants (tile-invariant): 40 VGPR
    float b1v[12], gv[12], bev[12], b2v[4];
    #pragma unroll
    for (int t = 0; t < 12; ++t) {
        b1v[t] = b1g[t * 16 + lrow];
        gv[t]  = gammag[t * 16 + lrow];
        bev[t] = betag[t * 16 + lrow];
    }
    #pragma unroll
    for (int t = 0; t < 4; ++t) b2v[t] = b2g[t * 16 + lrow];

    for (int wt = blockIdx.x * 4 + w; wt < NWT; wt += GRID * 4) {
        const int e0 = wt * 32;
        // lanes 0..31 hold row-idx of edge e0+le, lanes 32..63 hold col-idx
        int idxreg = ei[(lane >> 5) * NE + e0 + le];
        int ir = __shfl(idxreg, le, 64);
        int ic = __shfl(idxreg, le + 32, 64);

        // ---- gather 32x192 f32 -> bf16 into wave-private LDS ----
        // slot (j, lane): row le = lane&31, float4-col c4 = 2j + (lane>>5)
        const float* pr = nf + (size_t)ir * 64;
        const float* pc = nf + (size_t)ic * 64;
        const float* pe = ef + (size_t)(e0 + le) * 64;
        #pragma unroll
        for (int j = 0; j < 24; ++j) {
            int c4 = 2 * j + (lane >> 5);
            const float* src;
            if (j < 8)       src = pr + c4 * 4;          // node[row], cols 0..63
            else if (j < 16) src = pc + (c4 - 16) * 4;   // node[col], cols 64..127
            else             src = pe + (c4 - 32) * 4;   // edge,      cols 128..191
            float4 v = *(const float4*)src;
            uint2 pk;
            pk.x = f2b(v.x) | ((unsigned)f2b(v.y) << 16);
            pk.y = f2b(v.z) | ((unsigned)f2b(v.w) << 16);
            *(uint2*)&X[le * HP + c4 * 4] = pk;
        }

        // ---- GEMM1: 32x192 = X @ W1, B-frags streamed from L2 (d_ws) ----
        f32x4 acc1[2][12];
        #pragma unroll
        for (int m = 0; m < 2; ++m)
            #pragma unroll
            for (int t = 0; t < 12; ++t)
                acc1[m][t] = (f32x4){0.f, 0.f, 0.f, 0.f};
        #pragma unroll
        for (int ks = 0; ks < 6; ++ks) {
            short8 a0 = *(const short8*)&X[(lrow)      * HP + ks * 32 + lg * 8];
            short8 a1 = *(const short8*)&X[(16 + lrow) * HP + ks * 32 + lg * 8];
            #pragma unroll
            for (int t = 0; t < 12; ++t) {
                short8 bf = *(const short8*)(wsW + (size_t)(t * 6 + ks) * 64 + lane);
                acc1[0][t] = __builtin_amdgcn_mfma_f32_16x16x32_bf16(a0, bf, acc1[0][t], 0, 0, 0);
                acc1[1][t] = __builtin_amdgcn_mfma_f32_16x16x32_bf16(a1, bf, acc1[1][t], 0, 0, 0);
            }
        }

        // ---- +b1, LayerNorm (16-lane shfl reduce), relu, H -> X in place ----
        #pragma unroll
        for (int m = 0; m < 2; ++m) {
            #pragma unroll
            for (int rr = 0; rr < 4; ++rr) {
                float s = 0.f, q = 0.f;
                #pragma unroll
                for (int t = 0; t < 12; ++t) {
                    float v = acc1[m][t][rr] + b1v[t];
                    acc1[m][t][rr] = v;
                    s += v; q += v * v;
                }
                #pragma unroll
                for (int msk = 1; msk < 16; msk <<= 1) {
                    s += __shfl_xor(s, msk, 64);
                    q += __shfl_xor(q, msk, 64);
                }
                float mean = s * (1.f / 192.f);
                float var  = q * (1.f / 192.f) - mean * mean;
                float rsv  = rsqrtf(var + 1e-5f);
                int row = m * 16 + lg * 4 + rr;
                #pragma unroll
                for (int t = 0; t < 12; ++t) {
                    float v = (acc1[m][t][rr] - mean) * rsv * gv[t] + bev[t];
                    X[row * HP + t * 16 + lrow] = f2b(fmaxf(v, 0.f));
                }
            }
        }

        // ---- GEMM2: 32x64 = H @ W2 ----
        f32x4 acc2[2][4];
        #pragma unroll
        for (int m = 0; m < 2; ++m)
            #pragma unroll
            for (int t = 0; t < 4; ++t)
                acc2[m][t] = (f32x4){0.f, 0.f, 0.f, 0.f};
        #pragma unroll
        for (int ks = 0; ks < 6; ++ks) {
            short8 h0 = *(const short8*)&X[(lrow)      * HP + ks * 32 + lg * 8];
            short8 h1 = *(const short8*)&X[(16 + lrow) * HP + ks * 32 + lg * 8];
            #pragma unroll
            for (int t = 0; t < 4; ++t) {
                short8 bf = *(const short8*)(wsW + (size_t)(72 + t * 6 + ks) * 64 + lane);
                acc2[0][t] = __builtin_amdgcn_mfma_f32_16x16x32_bf16(h0, bf, acc2[0][t], 0, 0, 0);
                acc2[1][t] = __builtin_amdgcn_mfma_f32_16x16x32_bf16(h1, bf, acc2[1][t], 0, 0, 0);
            }
        }

        // ---- epilogue: + b2 + f32 edge residual, store ----
        #pragma unroll
        for (int m = 0; m < 2; ++m)
            #pragma unroll
            for (int t = 0; t < 4; ++t)
                #pragma unroll
                for (int rr = 0; rr < 4; ++rr) {
                    int row = m * 16 + lg * 4 + rr;
                    size_t o = (size_t)(e0 + row) * 64 + t * 16 + lrow;
                    out[o] = acc2[m][t][rr] + b2v[t] + ef[o];
                }
    }
}

extern "C" void kernel_launch(void* const* d_in, const int* in_sizes, int n_in,
                              void* d_out, int out_size, void* d_ws, size_t ws_size,
                              hipStream_t stream) {
    const float* nf    = (const float*)d_in[0];
    const float* ef    = (const float*)d_in[1];
    const int*   ei    = (const int*)d_in[2];
    const float* W1    = (const float*)d_in[3];
    const float* b1    = (const float*)d_in[4];
    const float* gamma = (const float*)d_in[5];
    const float* beta  = (const float*)d_in[6];
    const float* W2    = (const float*)d_in[7];
    const float* b2    = (const float*)d_in[8];
    float* out = (float*)d_out;
    uint4* wsW = (uint4*)d_ws;   // 98304 B used

    hipLaunchKernelGGL(pack_w, dim3(24), dim3(256), 0, stream, W1, W2, wsW);
    hipLaunchKernelGGL(edge_kernel, dim3(GRID), dim3(256), 0, stream,
                       nf, ef, ei, b1, gamma, beta, b2, (const uint4*)wsW, out);
}

// Round 5
// 680.938 us; speedup vs baseline: 2.1933x; 2.1933x over previous
//
#include <hip/hip_runtime.h>

#define NE     800000
#define NWT    50000          // 16-edge wave-tiles
#define GRID   256            // 1 block/CU, 8 waves -> 2048 waves total
#define STRIDE (GRID * 8)
#define HP     200            // ushort pitch of H rows (400 B)

typedef __attribute__((ext_vector_type(8))) short short8;   // 8 x bf16
typedef __attribute__((ext_vector_type(4))) float f32x4;

// f32 -> bf16 bits, round-to-nearest-even
__device__ __forceinline__ ushort f2b(float f) {
    unsigned u = __float_as_uint(f);
    return (ushort)((u + 0x7FFFu + ((u >> 16) & 1u)) >> 16);
}

// Pack W1 (192x192) and W2 (192x64) f32 -> bf16 MFMA B-fragments in d_ws.
// Entry e = t*6+k (e<72: W1; e>=72: W2). Lane l supplies
// B[k*32 + (l>>4)*8 + j][t*16 + (l&15)], j=0..7  (16 B per lane).
// (verified: R2/R4 passed with absmax 0.031)
__global__ void pack_w(const float* __restrict__ W1, const float* __restrict__ W2,
                       uint4* __restrict__ wsW)
{
    int i = blockIdx.x * 256 + threadIdx.x;     // 0..6143
    int lane = i & 63, e = i >> 6;
    const float* W; int N, t, k;
    if (e < 72) { W = W1; N = 192; t = e / 6; k = e - t * 6; }
    else        { int e2 = e - 72; W = W2; N = 64; t = e2 / 6; k = e2 - t * 6; }
    const float* p = W + (size_t)(k * 32 + (lane >> 4) * 8) * N + t * 16 + (lane & 15);
    ushort u[8];
    #pragma unroll
    for (int j = 0; j < 8; ++j) u[j] = f2b(p[(size_t)j * N]);
    uint4 d;
    d.x = u[0] | ((unsigned)u[1] << 16);
    d.y = u[2] | ((unsigned)u[3] << 16);
    d.z = u[4] | ((unsigned)u[5] << 16);
    d.w = u[6] | ((unsigned)u[7] << 16);
    wsW[i] = d;
}

// One wave = one 16-edge tile. X gathered straight into A-fragments (no LDS
// staging). W fragments in LDS (read-only, loaded once). H transposed through
// a wave-private LDS buffer. No __syncthreads in the main loop.
__global__ __launch_bounds__(512, 2)
void edge_kernel(const float* __restrict__ nf, const float* __restrict__ ef,
                 const int* __restrict__ ei,
                 const float* __restrict__ b1g, const float* __restrict__ gg,
                 const float* __restrict__ btg, const float* __restrict__ b2g,
                 const uint4* __restrict__ wsW, float* __restrict__ out)
{
    __shared__ __align__(16) uint4  Wl[6144];        // 98304 B: W1 then W2 frags
    __shared__ __align__(16) ushort Hs[8][16 * HP];  // 51200 B: per-wave H buffer

    const int tid  = threadIdx.x, w = tid >> 6, lane = tid & 63;
    const int lrow = lane & 15, lg = lane >> 4;
    ushort* H = Hs[w];

    // one-time: W fragments -> LDS
    #pragma unroll
    for (int i = 0; i < 12; ++i) Wl[i * 512 + tid] = wsW[i * 512 + tid];

    // per-lane epilogue constants (col = t*16 + lrow): 40 VGPR
    float b1v[12], gv[12], bev[12], b2v[4];
    #pragma unroll
    for (int t = 0; t < 12; ++t) {
        b1v[t] = b1g[t * 16 + lrow];
        gv[t]  = gg[t * 16 + lrow];
        bev[t] = btg[t * 16 + lrow];
    }
    #pragma unroll
    for (int t = 0; t < 4; ++t) b2v[t] = b2g[t * 16 + lrow];
    __syncthreads();                 // W visible; last barrier in the kernel

    int wt = blockIdx.x * 8 + w;

    // ---- prologue: gather tile(wt) into xv registers ----
    // lane (lrow,lg) needs X[row=lrow][ks*32 + lg*8 + j], j=0..7, ks=0..5
    float4 xv[12];
    {
        const int e0 = wt * 16;
        int iv = 0;
        if (lane < 32) iv = ei[(lane >> 4) * NE + e0 + lrow];
        int ir = __shfl(iv, lrow, 64);
        int ic = __shfl(iv, 16 + lrow, 64);
        const float* pr = nf + (size_t)ir * 64 + lg * 8;
        const float* pc = nf + (size_t)ic * 64 + lg * 8;
        const float* pe = ef + (size_t)(e0 + lrow) * 64 + lg * 8;
        xv[0]  = *(const float4*)(pr);      xv[1]  = *(const float4*)(pr + 4);
        xv[2]  = *(const float4*)(pr + 32); xv[3]  = *(const float4*)(pr + 36);
        xv[4]  = *(const float4*)(pc);      xv[5]  = *(const float4*)(pc + 4);
        xv[6]  = *(const float4*)(pc + 32); xv[7]  = *(const float4*)(pc + 36);
        xv[8]  = *(const float4*)(pe);      xv[9]  = *(const float4*)(pe + 4);
        xv[10] = *(const float4*)(pe + 32); xv[11] = *(const float4*)(pe + 36);
    }

    for (; wt < NWT; wt += STRIDE) {
        const int e0 = wt * 16;
        const int wn = wt + STRIDE;
        const bool hasNext = wn < NWT;

        // ---- convert xv -> A-fragments xf[ks] ----
        short8 xf[6];
        #pragma unroll
        for (int ks = 0; ks < 6; ++ks) {
            float4 a = xv[2 * ks], b = xv[2 * ks + 1];
            xf[ks][0] = (short)f2b(a.x); xf[ks][1] = (short)f2b(a.y);
            xf[ks][2] = (short)f2b(a.z); xf[ks][3] = (short)f2b(a.w);
            xf[ks][4] = (short)f2b(b.x); xf[ks][5] = (short)f2b(b.y);
            xf[ks][6] = (short)f2b(b.z); xf[ks][7] = (short)f2b(b.w);
        }

        // ---- issue next tile's gather (in flight across GEMM1/LN/GEMM2) ----
        if (hasNext) {
            const int e1 = wn * 16;
            int iv = 0;
            if (lane < 32) iv = ei[(lane >> 4) * NE + e1 + lrow];
            int ir = __shfl(iv, lrow, 64);
            int ic = __shfl(iv, 16 + lrow, 64);
            const float* pr = nf + (size_t)ir * 64 + lg * 8;
            const float* pc = nf + (size_t)ic * 64 + lg * 8;
            const float* pe = ef + (size_t)(e1 + lrow) * 64 + lg * 8;
            xv[0]  = *(const float4*)(pr);      xv[1]  = *(const float4*)(pr + 4);
            xv[2]  = *(const float4*)(pr + 32); xv[3]  = *(const float4*)(pr + 36);
            xv[4]  = *(const float4*)(pc);      xv[5]  = *(const float4*)(pc + 4);
            xv[6]  = *(const float4*)(pc + 32); xv[7]  = *(const float4*)(pc + 36);
            xv[8]  = *(const float4*)(pe);      xv[9]  = *(const float4*)(pe + 4);
            xv[10] = *(const float4*)(pe + 32); xv[11] = *(const float4*)(pe + 36);
        }

        // ---- GEMM1: 16x192 = X @ W1, A from registers, B from LDS ----
        f32x4 acc1[12];
        #pragma unroll
        for (int t = 0; t < 12; ++t) acc1[t] = (f32x4){0.f, 0.f, 0.f, 0.f};
        #pragma unroll
        for (int ks = 0; ks < 6; ++ks) {
            #pragma unroll
            for (int t = 0; t < 12; ++t) {
                short8 bf = *(const short8*)&Wl[(t * 6 + ks) * 64 + lane];
                acc1[t] = __builtin_amdgcn_mfma_f32_16x16x32_bf16(xf[ks], bf, acc1[t], 0, 0, 0);
            }
        }

        // ---- +b1, LayerNorm (16-lane shfl reduce), relu, H -> wave LDS ----
        // D layout: row = lg*4+rr, col = t*16+lrow
        #pragma unroll
        for (int rr = 0; rr < 4; ++rr) {
            float s = 0.f, q = 0.f;
            #pragma unroll
            for (int t = 0; t < 12; ++t) {
                float v = acc1[t][rr] + b1v[t];
                acc1[t][rr] = v;
                s += v; q += v * v;
            }
            #pragma unroll
            for (int msk = 1; msk < 16; msk <<= 1) {
                s += __shfl_xor(s, msk, 64);
                q += __shfl_xor(q, msk, 64);
            }
            float mean = s * (1.f / 192.f);
            float var  = q * (1.f / 192.f) - mean * mean;
            float rsv  = rsqrtf(var + 1e-5f);
            #pragma unroll
            for (int t = 0; t < 12; ++t) {
                float v = (acc1[t][rr] - mean) * rsv * gv[t] + bev[t];
                H[(lg * 4 + rr) * HP + t * 16 + lrow] = f2b(fmaxf(v, 0.f));
            }
        }

        // ---- GEMM2: 16x64 = H @ W2, A from wave LDS (in-wave dep, no barrier) ----
        f32x4 acc2[4];
        #pragma unroll
        for (int t = 0; t < 4; ++t) acc2[t] = (f32x4){0.f, 0.f, 0.f, 0.f};
        #pragma unroll
        for (int ks = 0; ks < 6; ++ks) {
            short8 hf = *(const short8*)&H[lrow * HP + ks * 32 + lg * 8];
            #pragma unroll
            for (int t = 0; t < 4; ++t) {
                short8 bf = *(const short8*)&Wl[(72 + t * 6 + ks) * 64 + lane];
                acc2[t] = __builtin_amdgcn_mfma_f32_16x16x32_bf16(hf, bf, acc2[t], 0, 0, 0);
            }
        }

        // ---- epilogue: + b2 + f32 edge residual (L1/L2-hot), store ----
        #pragma unroll
        for (int t = 0; t < 4; ++t)
            #pragma unroll
            for (int rr = 0; rr < 4; ++rr) {
                int row = lg * 4 + rr;
                size_t o = (size_t)(e0 + row) * 64 + t * 16 + lrow;
                out[o] = acc2[t][rr] + b2v[t] + ef[o];
            }
    }
}

extern "C" void kernel_launch(void* const* d_in, const int* in_sizes, int n_in,
                              void* d_out, int out_size, void* d_ws, size_t ws_size,
                              hipStream_t stream) {
    const float* nf    = (const float*)d_in[0];
    const float* ef    = (const float*)d_in[1];
    const int*   ei    = (const int*)d_in[2];
    const float* W1    = (const float*)d_in[3];
    const float* b1    = (const float*)d_in[4];
    const float* gamma = (const float*)d_in[5];
    const float* beta  = (const float*)d_in[6];
    const float* W2    = (const float*)d_in[7];
    const float* b2    = (const float*)d_in[8];
    float* out = (float*)d_out;
    uint4* wsW = (uint4*)d_ws;   // 98304 B used

    hipLaunchKernelGGL(pack_w, dim3(24), dim3(256), 0, stream, W1, W2, wsW);
    hipLaunchKernelGGL(edge_kernel, dim3(GRID), dim3(512), 0, stream,
                       nf, ef, ei, b1, gamma, beta, b2, (const uint4*)wsW, out);
}

// Round 6
// 584.182 us; speedup vs baseline: 2.5565x; 1.1656x over previous
//
#include <hip/hip_runtime.h>

#define NE     800000
#define NWT    50000          // 16-edge wave-tiles
#define GRID   256            // 1 block/CU, 8 waves -> 2048 waves total
#define STRIDE (GRID * 8)
#define HP     200            // ushort pitch of H rows (400 B)

typedef __attribute__((ext_vector_type(8))) short short8;   // 8 x bf16
typedef __attribute__((ext_vector_type(4))) float f32x4;

// f32 -> bf16 bits, round-to-nearest-even
__device__ __forceinline__ ushort f2b(float f) {
    unsigned u = __float_as_uint(f);
    return (ushort)((u + 0x7FFFu + ((u >> 16) & 1u)) >> 16);
}

// Pack W1 (192x192) and W2 (192x64) f32 -> bf16 MFMA B-fragments in d_ws.
// Entry e = t*6+k (e<72: W1; e>=72: W2). Lane l supplies
// B[k*32 + (l>>4)*8 + j][t*16 + (l&15)], j=0..7  (16 B per lane).
// (verified: R2/R4/R5 passed with absmax 0.031)
__global__ void pack_w(const float* __restrict__ W1, const float* __restrict__ W2,
                       uint4* __restrict__ wsW)
{
    int i = blockIdx.x * 256 + threadIdx.x;     // 0..6143
    int lane = i & 63, e = i >> 6;
    const float* W; int N, t, k;
    if (e < 72) { W = W1; N = 192; t = e / 6; k = e - t * 6; }
    else        { int e2 = e - 72; W = W2; N = 64; t = e2 / 6; k = e2 - t * 6; }
    const float* p = W + (size_t)(k * 32 + (lane >> 4) * 8) * N + t * 16 + (lane & 15);
    ushort u[8];
    #pragma unroll
    for (int j = 0; j < 8; ++j) u[j] = f2b(p[(size_t)j * N]);
    uint4 d;
    d.x = u[0] | ((unsigned)u[1] << 16);
    d.y = u[2] | ((unsigned)u[3] << 16);
    d.z = u[4] | ((unsigned)u[5] << 16);
    d.w = u[6] | ((unsigned)u[7] << 16);
    wsW[i] = d;
}

// One wave = one 16-edge tile. X gathered straight into A-fragments (no LDS
// staging, no cross-tile register prefetch -> bounded register pressure).
// W fragments in LDS (loaded once). H transposed through a wave-private LDS
// buffer. No __syncthreads in the main loop.
__global__ __launch_bounds__(512, 2)
void edge_kernel(const float* __restrict__ nf, const float* __restrict__ ef,
                 const int* __restrict__ ei,
                 const float* __restrict__ b1g, const float* __restrict__ gg,
                 const float* __restrict__ btg, const float* __restrict__ b2g,
                 const uint4* __restrict__ wsW, float* __restrict__ out)
{
    __shared__ __align__(16) uint4  Wl[6144];        // 98304 B: W1 then W2 frags
    __shared__ __align__(16) ushort Hs[8][16 * HP];  // 51200 B: per-wave H buffer

    const int tid  = threadIdx.x, w = tid >> 6, lane = tid & 63;
    const int lrow = lane & 15, lg = lane >> 4;
    ushort* H = Hs[w];

    // one-time: W fragments -> LDS
    #pragma unroll
    for (int i = 0; i < 12; ++i) Wl[i * 512 + tid] = wsW[i * 512 + tid];

    // per-lane epilogue constants (col = t*16 + lrow): 40 VGPR
    float b1v[12], gv[12], bev[12], b2v[4];
    #pragma unroll
    for (int t = 0; t < 12; ++t) {
        b1v[t] = b1g[t * 16 + lrow];
        gv[t]  = gg[t * 16 + lrow];
        bev[t] = btg[t * 16 + lrow];
    }
    #pragma unroll
    for (int t = 0; t < 4; ++t) b2v[t] = b2g[t * 16 + lrow];
    __syncthreads();                 // W visible; last barrier in the kernel

    for (int wt = blockIdx.x * 8 + w; wt < NWT; wt += STRIDE) {
        const int e0 = wt * 16;

        // ---- gather tile into A-fragments ----
        // lane (lrow,lg) holds X[row=lrow][ks*32 + lg*8 + j], j=0..7
        int iv = 0;
        if (lane < 32) iv = ei[(lane >> 4) * NE + e0 + lrow];
        int ir = __shfl(iv, lrow, 64);
        int ic = __shfl(iv, 16 + lrow, 64);
        const float* pr = nf + (size_t)ir * 64 + lg * 8;
        const float* pc = nf + (size_t)ic * 64 + lg * 8;
        const float* pe = ef + (size_t)(e0 + lrow) * 64 + lg * 8;
        float4 xv[12];
        xv[0]  = *(const float4*)(pr);      xv[1]  = *(const float4*)(pr + 4);
        xv[2]  = *(const float4*)(pr + 32); xv[3]  = *(const float4*)(pr + 36);
        xv[4]  = *(const float4*)(pc);      xv[5]  = *(const float4*)(pc + 4);
        xv[6]  = *(const float4*)(pc + 32); xv[7]  = *(const float4*)(pc + 36);
        xv[8]  = *(const float4*)(pe);      xv[9]  = *(const float4*)(pe + 4);
        xv[10] = *(const float4*)(pe + 32); xv[11] = *(const float4*)(pe + 36);

        short8 xf[6];
        #pragma unroll
        for (int ks = 0; ks < 6; ++ks) {
            float4 a = xv[2 * ks], b = xv[2 * ks + 1];
            xf[ks][0] = (short)f2b(a.x); xf[ks][1] = (short)f2b(a.y);
            xf[ks][2] = (short)f2b(a.z); xf[ks][3] = (short)f2b(a.w);
            xf[ks][4] = (short)f2b(b.x); xf[ks][5] = (short)f2b(b.y);
            xf[ks][6] = (short)f2b(b.z); xf[ks][7] = (short)f2b(b.w);
        }

        // ---- GEMM1: 16x192 = X @ W1, A from registers, B from LDS ----
        f32x4 acc1[12];
        #pragma unroll
        for (int t = 0; t < 12; ++t) acc1[t] = (f32x4){0.f, 0.f, 0.f, 0.f};
        #pragma unroll
        for (int ks = 0; ks < 6; ++ks) {
            #pragma unroll
            for (int t = 0; t < 12; ++t) {
                short8 bf = *(const short8*)&Wl[(t * 6 + ks) * 64 + lane];
                acc1[t] = __builtin_amdgcn_mfma_f32_16x16x32_bf16(xf[ks], bf, acc1[t], 0, 0, 0);
            }
        }

        // ---- +b1, LayerNorm (16-lane shfl reduce), relu, H -> wave LDS ----
        // D layout: row = lg*4+rr, col = t*16+lrow
        #pragma unroll
        for (int rr = 0; rr < 4; ++rr) {
            float s = 0.f, q = 0.f;
            #pragma unroll
            for (int t = 0; t < 12; ++t) {
                float v = acc1[t][rr] + b1v[t];
                acc1[t][rr] = v;
                s += v; q += v * v;
            }
            #pragma unroll
            for (int msk = 1; msk < 16; msk <<= 1) {
                s += __shfl_xor(s, msk, 64);
                q += __shfl_xor(q, msk, 64);
            }
            float mean = s * (1.f / 192.f);
            float var  = q * (1.f / 192.f) - mean * mean;
            float rsv  = rsqrtf(var + 1e-5f);
            #pragma unroll
            for (int t = 0; t < 12; ++t) {
                float v = (acc1[t][rr] - mean) * rsv * gv[t] + bev[t];
                H[(lg * 4 + rr) * HP + t * 16 + lrow] = f2b(fmaxf(v, 0.f));
            }
        }

        // ---- GEMM2: 16x64 = H @ W2, A from wave LDS (in-wave dep, no barrier) ----
        f32x4 acc2[4];
        #pragma unroll
        for (int t = 0; t < 4; ++t) acc2[t] = (f32x4){0.f, 0.f, 0.f, 0.f};
        #pragma unroll
        for (int ks = 0; ks < 6; ++ks) {
            short8 hf = *(const short8*)&H[lrow * HP + ks * 32 + lg * 8];
            #pragma unroll
            for (int t = 0; t < 4; ++t) {
                short8 bf = *(const short8*)&Wl[(72 + t * 6 + ks) * 64 + lane];
                acc2[t] = __builtin_amdgcn_mfma_f32_16x16x32_bf16(hf, bf, acc2[t], 0, 0, 0);
            }
        }

        // ---- epilogue: + b2 + f32 edge residual (L2-hot re-read), store ----
        #pragma unroll
        for (int t = 0; t < 4; ++t)
            #pragma unroll
            for (int rr = 0; rr < 4; ++rr) {
                int row = lg * 4 + rr;
                size_t o = (size_t)(e0 + row) * 64 + t * 16 + lrow;
                out[o] = acc2[t][rr] + b2v[t] + ef[o];
            }
    }
}

extern "C" void kernel_launch(void* const* d_in, const int* in_sizes, int n_in,
                              void* d_out, int out_size, void* d_ws, size_t ws_size,
                              hipStream_t stream) {
    const float* nf    = (const float*)d_in[0];
    const float* ef    = (const float*)d_in[1];
    const int*   ei    = (const int*)d_in[2];
    const float* W1    = (const float*)d_in[3];
    const float* b1    = (const float*)d_in[4];
    const float* gamma = (const float*)d_in[5];
    const float* beta  = (const float*)d_in[6];
    const float* W2    = (const float*)d_in[7];
    const float* b2    = (const float*)d_in[8];
    float* out = (float*)d_out;
    uint4* wsW = (uint4*)d_ws;   // 98304 B used

    hipLaunchKernelGGL(pack_w, dim3(24), dim3(256), 0, stream, W1, W2, wsW);
    hipLaunchKernelGGL(edge_kernel, dim3(GRID), dim3(512), 0, stream,
                       nf, ef, ei, b1, gamma, beta, b2, (const uint4*)wsW, out);
}

// Round 7
// 582.377 us; speedup vs baseline: 2.5645x; 1.0031x over previous
//
#include <hip/hip_runtime.h>

#define NE     800000
#define NWT    50000          // 16-edge wave-tiles
#define GRID   256            // 1 block/CU, 8 waves -> 2048 waves total
#define STRIDE (GRID * 8)
#define HP     200            // ushort pitch of H rows (400 B)

typedef __attribute__((ext_vector_type(8))) short short8;   // 8 x bf16
typedef __attribute__((ext_vector_type(4))) float f32x4;

// f32 -> bf16 bits, round-to-nearest-even
__device__ __forceinline__ ushort f2b(float f) {
    unsigned u = __float_as_uint(f);
    return (ushort)((u + 0x7FFFu + ((u >> 16) & 1u)) >> 16);
}

// Pack W1 (192x192) and W2 (192x64) f32 -> bf16 MFMA B-fragments in d_ws.
// Entry e = t*6+k (e<72: W1; e>=72: W2). Lane l supplies
// B[k*32 + (l>>4)*8 + j][t*16 + (l&15)], j=0..7  (16 B per lane).
// (verified: R2/R4/R5/R6 passed with absmax 0.031)
__global__ void pack_w(const float* __restrict__ W1, const float* __restrict__ W2,
                       uint4* __restrict__ wsW)
{
    int i = blockIdx.x * 256 + threadIdx.x;     // 0..6143
    int lane = i & 63, e = i >> 6;
    const float* W; int N, t, k;
    if (e < 72) { W = W1; N = 192; t = e / 6; k = e - t * 6; }
    else        { int e2 = e - 72; W = W2; N = 64; t = e2 / 6; k = e2 - t * 6; }
    const float* p = W + (size_t)(k * 32 + (lane >> 4) * 8) * N + t * 16 + (lane & 15);
    ushort u[8];
    #pragma unroll
    for (int j = 0; j < 8; ++j) u[j] = f2b(p[(size_t)j * N]);
    uint4 d;
    d.x = u[0] | ((unsigned)u[1] << 16);
    d.y = u[2] | ((unsigned)u[3] << 16);
    d.z = u[4] | ((unsigned)u[5] << 16);
    d.w = u[6] | ((unsigned)u[7] << 16);
    wsW[i] = d;
}

// One wave = one 16-edge tile. X gathered straight into A-fragments.
// W fragments in LDS (loaded once). H transposed through a wave-private LDS
// buffer. gamma/beta/b2 in LDS, loaded into short-lived locals per phase.
// No __syncthreads in the main loop.
__global__ __launch_bounds__(512, 1)
void edge_kernel(const float* __restrict__ nf, const float* __restrict__ ef,
                 const int* __restrict__ ei,
                 const float* __restrict__ b1g, const float* __restrict__ gg,
                 const float* __restrict__ btg, const float* __restrict__ b2g,
                 const uint4* __restrict__ wsW, float* __restrict__ out)
{
    __shared__ __align__(16) uint4  Wl[6144];        // 98304 B: W1 then W2 frags
    __shared__ __align__(16) ushort Hs[8][16 * HP];  // 51200 B: per-wave H buffer
    __shared__ float cs[448];                        // gamma[0:192] beta[192:384] b2[384:448]

    const int tid  = threadIdx.x, w = tid >> 6, lane = tid & 63;
    const int lrow = lane & 15, lg = lane >> 4;
    ushort* H = Hs[w];

    // one-time: W fragments -> LDS, epilogue consts -> LDS
    #pragma unroll
    for (int i = 0; i < 12; ++i) Wl[i * 512 + tid] = wsW[i * 512 + tid];
    if (tid < 448)
        cs[tid] = (tid < 192) ? gg[tid] : (tid < 384) ? btg[tid - 192] : b2g[tid - 384];

    // b1 stays in registers (needed inside the LN sum): 12 VGPR
    float b1v[12];
    #pragma unroll
    for (int t = 0; t < 12; ++t) b1v[t] = b1g[t * 16 + lrow];
    __syncthreads();                 // W + cs visible; last barrier in the kernel

    for (int wt = blockIdx.x * 8 + w; wt < NWT; wt += STRIDE) {
        const int e0 = wt * 16;

        // ---- gather tile into A-fragments ----
        // lane (lrow,lg) holds X[row=lrow][ks*32 + lg*8 + j], j=0..7
        int iv = 0;
        if (lane < 32) iv = ei[(lane >> 4) * NE + e0 + lrow];
        int ir = __shfl(iv, lrow, 64);
        int ic = __shfl(iv, 16 + lrow, 64);
        const float* pr = nf + (size_t)ir * 64 + lg * 8;
        const float* pc = nf + (size_t)ic * 64 + lg * 8;
        const float* pe = ef + (size_t)(e0 + lrow) * 64 + lg * 8;
        float4 xv[12];
        xv[0]  = *(const float4*)(pr);      xv[1]  = *(const float4*)(pr + 4);
        xv[2]  = *(const float4*)(pr + 32); xv[3]  = *(const float4*)(pr + 36);
        xv[4]  = *(const float4*)(pc);      xv[5]  = *(const float4*)(pc + 4);
        xv[6]  = *(const float4*)(pc + 32); xv[7]  = *(const float4*)(pc + 36);
        xv[8]  = *(const float4*)(pe);      xv[9]  = *(const float4*)(pe + 4);
        xv[10] = *(const float4*)(pe + 32); xv[11] = *(const float4*)(pe + 36);

        short8 xf[6];
        #pragma unroll
        for (int ks = 0; ks < 6; ++ks) {
            float4 a = xv[2 * ks], b = xv[2 * ks + 1];
            xf[ks][0] = (short)f2b(a.x); xf[ks][1] = (short)f2b(a.y);
            xf[ks][2] = (short)f2b(a.z); xf[ks][3] = (short)f2b(a.w);
            xf[ks][4] = (short)f2b(b.x); xf[ks][5] = (short)f2b(b.y);
            xf[ks][6] = (short)f2b(b.z); xf[ks][7] = (short)f2b(b.w);
        }

        // ---- GEMM1: 16x192 = X @ W1, A from registers, B from LDS ----
        f32x4 acc1[12];
        #pragma unroll
        for (int t = 0; t < 12; ++t) acc1[t] = (f32x4){0.f, 0.f, 0.f, 0.f};
        #pragma unroll
        for (int ks = 0; ks < 6; ++ks) {
            #pragma unroll
            for (int t = 0; t < 12; ++t) {
                short8 bf = *(const short8*)&Wl[(t * 6 + ks) * 64 + lane];
                acc1[t] = __builtin_amdgcn_mfma_f32_16x16x32_bf16(xf[ks], bf, acc1[t], 0, 0, 0);
            }
        }

        // ---- +b1, LayerNorm (16-lane shfl reduce), relu, H -> wave LDS ----
        // D layout: row = lg*4+rr, col = t*16+lrow
        float gvt[12], bvt[12];
        #pragma unroll
        for (int t = 0; t < 12; ++t) {
            gvt[t] = cs[t * 16 + lrow];
            bvt[t] = cs[192 + t * 16 + lrow];
        }
        #pragma unroll
        for (int rr = 0; rr < 4; ++rr) {
            float s = 0.f, q = 0.f;
            #pragma unroll
            for (int t = 0; t < 12; ++t) {
                float v = acc1[t][rr] + b1v[t];
                acc1[t][rr] = v;
                s += v; q += v * v;
            }
            #pragma unroll
            for (int msk = 1; msk < 16; msk <<= 1) {
                s += __shfl_xor(s, msk, 64);
                q += __shfl_xor(q, msk, 64);
            }
            float mean = s * (1.f / 192.f);
            float var  = q * (1.f / 192.f) - mean * mean;
            float rsv  = rsqrtf(var + 1e-5f);
            #pragma unroll
            for (int t = 0; t < 12; ++t) {
                float v = (acc1[t][rr] - mean) * rsv * gvt[t] + bvt[t];
                H[(lg * 4 + rr) * HP + t * 16 + lrow] = f2b(fmaxf(v, 0.f));
            }
        }

        // ---- GEMM2: 16x64 = H @ W2, A from wave LDS (in-wave dep, no barrier) ----
        f32x4 acc2[4];
        #pragma unroll
        for (int t = 0; t < 4; ++t) acc2[t] = (f32x4){0.f, 0.f, 0.f, 0.f};
        #pragma unroll
        for (int ks = 0; ks < 6; ++ks) {
            short8 hf = *(const short8*)&H[lrow * HP + ks * 32 + lg * 8];
            #pragma unroll
            for (int t = 0; t < 4; ++t) {
                short8 bf = *(const short8*)&Wl[(72 + t * 6 + ks) * 64 + lane];
                acc2[t] = __builtin_amdgcn_mfma_f32_16x16x32_bf16(hf, bf, acc2[t], 0, 0, 0);
            }
        }

        // ---- epilogue: + b2 + f32 edge residual (L2-hot re-read), store ----
        float b2v[4];
        #pragma unroll
        for (int t = 0; t < 4; ++t) b2v[t] = cs[384 + t * 16 + lrow];
        #pragma unroll
        for (int t = 0; t < 4; ++t)
            #pragma unroll
            for (int rr = 0; rr < 4; ++rr) {
                int row = lg * 4 + rr;
                size_t o = (size_t)(e0 + row) * 64 + t * 16 + lrow;
                out[o] = acc2[t][rr] + b2v[t] + ef[o];
            }
    }
}

extern "C" void kernel_launch(void* const* d_in, const int* in_sizes, int n_in,
                              void* d_out, int out_size, void* d_ws, size_t ws_size,
                              hipStream_t stream) {
    const float* nf    = (const float*)d_in[0];
    const float* ef    = (const float*)d_in[1];
    const int*   ei    = (const int*)d_in[2];
    const float* W1    = (const float*)d_in[3];
    const float* b1    = (const float*)d_in[4];
    const float* gamma = (const float*)d_in[5];
    const float* beta  = (const float*)d_in[6];
    const float* W2    = (const float*)d_in[7];
    const float* b2    = (const float*)d_in[8];
    float* out = (float*)d_out;
    uint4* wsW = (uint4*)d_ws;   // 98304 B used

    hipLaunchKernelGGL(pack_w, dim3(24), dim3(256), 0, stream, W1, W2, wsW);
    hipLaunchKernelGGL(edge_kernel, dim3(GRID), dim3(512), 0, stream,
                       nf, ef, ei, b1, gamma, beta, b2, (const uint4*)wsW, out);
}